// Round 5
// baseline (820.005 us; speedup 1.0000x reference)
//
#include <hip/hip_runtime.h>
#include <stdint.h>

typedef __attribute__((ext_vector_type(8))) short short8;
typedef __attribute__((ext_vector_type(4))) float f32x4;

#define TT 512
#define LSTR 72    // sZ row stride in ushorts (36 dw; 36/4=9 odd -> even bank tiling)
#define XS 516     // sX row stride in floats

static __device__ __forceinline__ uint32_t f2bf_u(float f){
  union { float f; uint32_t u; } v; v.f = f;
  return (v.u + 0x7fffu + ((v.u >> 16) & 1u)) >> 16;
}
static __device__ __forceinline__ float fast_rcp(float x){ return __builtin_amdgcn_rcpf(x); }
static __device__ __forceinline__ float fast_exp2(float x){ return __builtin_amdgcn_exp2f(x); }
// sigmoid/tanh, clamp-free (exp2 saturates; rcp(inf)=0)
static __device__ __forceinline__ float sigf(float x){
  return fast_rcp(1.f + fast_exp2(-1.4426950408889634f * x));
}
static __device__ __forceinline__ float tanh_f(float x){
  return fmaf(-2.f, fast_rcp(1.f + fast_exp2(2.8853900817779268f * x)), 1.f);
}
// unit-permutation: h stored at position p holds unit sigma(p);
// lane (wv,quad) then writes its two h values at consecutive positions -> one b32 write.
static __device__ __forceinline__ int sigma_p(int k){
  return 8 * (k >> 3) + ((k >> 1) & 3) + 4 * (k & 1);
}
// LDS-only barrier: waits ds ops, leaves global ops in flight.
static __device__ __forceinline__ void lds_barrier(){
  asm volatile("s_waitcnt lgkmcnt(0)" ::: "memory");
  __builtin_amdgcn_s_barrier();
}
#define MF(A,B,C) __builtin_amdgcn_mfma_f32_16x16x32_bf16((A),(B),(C),0,0,0)

// ==================== Layer 0 ====================
// 512 thr / 8 waves; wave w owns rowtiles 2w,2w+1 (units 8w+quad, 8w+4+quad per lane)
__global__ __launch_bounds__(512, 2) void lstm_l0(
    const float* __restrict__ x,   // [B][3][T]
    const float* __restrict__ Wih_f, const float* __restrict__ Whh_f,
    const float* __restrict__ bih_f, const float* __restrict__ bhh_f,
    const float* __restrict__ Wih_b, const float* __restrict__ Whh_b,
    const float* __restrict__ bih_b, const float* __restrict__ bhh_b,
    unsigned short* __restrict__ y0)  // [B][T][128] bf16, unit-permuted within each dir block
{
  const int tid = threadIdx.x;
  const int wv = tid >> 6, lane = tid & 63;
  const int quad = lane >> 4, m16 = lane & 15;
  const int dir = blockIdx.y;
  const int bbase = blockIdx.x * 8;
  const float* Wih = dir ? Wih_b : Wih_f;
  const float* Whh = dir ? Whh_b : Whh_f;
  const float* bih = dir ? bih_b : bih_f;
  const float* bhh = dir ? bhh_b : bhh_f;

  __shared__ __align__(16) unsigned short sZ[2][16][LSTR];
  __shared__ __align__(16) float sX[24 * XS];

  // A-frags: tile rows rho -> gate rho&3, unit 4rt+(rho>>2). Columns permuted by sigma.
  short8 aH[2][2], aX[2];
  f32x4 biasv[2];
  const int gm = (m16 & 3) * 64 + (m16 >> 2);
  #pragma unroll
  for (int i = 0; i < 2; i++){
    const int rt = 2 * wv + i;
    const int g = gm + 4 * rt;
    #pragma unroll
    for (int c = 0; c < 2; c++){
      short8 r;
      #pragma unroll
      for (int j = 0; j < 8; j++)
        r[j] = (short)f2bf_u(Whh[g * 64 + sigma_p(c * 32 + quad * 8 + j)]);
      aH[i][c] = r;
    }
    short8 ax = {0,0,0,0,0,0,0,0};
    if (quad == 0){
      ax[0] = (short)f2bf_u(Wih[g * 3 + 0]);
      ax[1] = (short)f2bf_u(Wih[g * 3 + 1]);
      ax[2] = (short)f2bf_u(Wih[g * 3 + 2]);
    }
    aX[i] = ax;
    const int gu = 4 * rt + quad;
    #pragma unroll
    for (int r = 0; r < 4; r++) biasv[i][r] = bih[r * 64 + gu] + bhh[r * 64 + gu];
  }

  for (int idx = tid; idx < 2 * 16 * LSTR; idx += 512)
    ((unsigned short*)sZ)[idx] = 0;
  for (int i4 = tid; i4 < 3072; i4 += 512){
    const int row = i4 >> 7, t4 = (i4 & 127) * 4;
    *(float4*)&sX[row * XS + t4] = *(const float4*)(x + (size_t)bbase * 1536 + row * 512 + t4);
  }
  __syncthreads();

  const int xrow = 3 * (m16 & 7);
  float c0 = 0.f, c1 = 0.f;
  f32x4 accX[2];
  {
    const int t0 = dir ? (TT - 1) : 0;
    short8 bx = {0,0,0,0,0,0,0,0};
    if (quad == 0){
      bx[0] = (short)f2bf_u(sX[xrow * XS + t0]);
      bx[1] = (short)f2bf_u(sX[(xrow + 1) * XS + t0]);
      bx[2] = (short)f2bf_u(sX[(xrow + 2) * XS + t0]);
    }
    accX[0] = MF(aX[0], bx, biasv[0]);
    accX[1] = MF(aX[1], bx, biasv[1]);
  }

  const int hpos = 4 * wv + quad;                 // dword index within sZ row
  const size_t ybase = (size_t)(bbase + m16) * TT; // valid when m16<8

  for (int s = 0; s < TT; s++){
    const int p = s & 1, p1 = p ^ 1;
    const int t = dir ? (TT - 1 - s) : s;

    short8 bh0 = *(const short8*)&sZ[p][m16][     quad * 8];
    short8 bh1 = *(const short8*)&sZ[p][m16][32 + quad * 8];

    f32x4 a0, a1;
    a0 = MF(aH[0][0], bh0, accX[0]);  a1 = MF(aH[1][0], bh0, accX[1]);
    a0 = MF(aH[0][1], bh1, a0);       a1 = MF(aH[1][1], bh1, a1);

    float h0, h1;
    { float ip = sigf(a0[0]), fp = sigf(a0[1]), gp = tanh_f(a0[2]), op = sigf(a0[3]);
      c0 = fmaf(fp, c0, ip * gp); h0 = op * tanh_f(c0); }
    { float ip = sigf(a1[0]), fp = sigf(a1[1]), gp = tanh_f(a1[2]), op = sigf(a1[3]);
      c1 = fmaf(fp, c1, ip * gp); h1 = op * tanh_f(c1); }

    if (m16 < 8){
      const uint32_t hw = f2bf_u(h0) | (f2bf_u(h1) << 16);
      ((uint32_t*)&sZ[p1][m16][0])[hpos] = hw;
      *(uint32_t*)(y0 + (ybase + t) * 128 + dir * 64 + 2 * hpos) = hw;
    }
    // shadow: accX for s+1 (hidden behind barrier wait)
    {
      const int sn = (s + 1 < TT) ? (s + 1) : s;
      const int tn = dir ? (TT - 1 - sn) : sn;
      short8 bx = {0,0,0,0,0,0,0,0};
      if (quad == 0){
        bx[0] = (short)f2bf_u(sX[xrow * XS + tn]);
        bx[1] = (short)f2bf_u(sX[(xrow + 1) * XS + tn]);
        bx[2] = (short)f2bf_u(sX[(xrow + 2) * XS + tn]);
      }
      accX[0] = MF(aX[0], bx, biasv[0]);
      accX[1] = MF(aX[1], bx, biasv[1]);
    }
    lds_barrier();
  }
}

// ==================== Layer 1 ====================
__global__ __launch_bounds__(512, 2) void lstm_l1(
    const unsigned short* __restrict__ y0,  // [B][T][128] bf16, unit-permuted
    const float* __restrict__ Wih_f, const float* __restrict__ Whh_f,
    const float* __restrict__ bih_f, const float* __restrict__ bhh_f,
    const float* __restrict__ Wih_b, const float* __restrict__ Whh_b,
    const float* __restrict__ bih_b, const float* __restrict__ bhh_b,
    float* __restrict__ hT)                 // [B][128] fp32, canonical order
{
  const int tid = threadIdx.x;
  const int wv = tid >> 6, lane = tid & 63;
  const int quad = lane >> 4, m16 = lane & 15;
  const int dir = blockIdx.y;
  const int bbase = blockIdx.x * 8;
  const float* Wih = dir ? Wih_b : Wih_f;
  const float* Whh = dir ? Whh_b : Whh_f;
  const float* bih = dir ? bih_b : bih_f;
  const float* bhh = dir ? bhh_b : bhh_f;

  __shared__ __align__(16) unsigned short sZ[2][16][LSTR];

  short8 aY[2][4], aH[2][2];
  f32x4 biasv[2];
  const int gm = (m16 & 3) * 64 + (m16 >> 2);
  #pragma unroll
  for (int i = 0; i < 2; i++){
    const int rt = 2 * wv + i;
    const int g = gm + 4 * rt;
    #pragma unroll
    for (int kt = 0; kt < 4; kt++){
      short8 r;
      #pragma unroll
      for (int j = 0; j < 8; j++){
        const int q = kt * 32 + quad * 8 + j;
        const int col = (q < 64) ? sigma_p(q) : (64 + sigma_p(q - 64));
        r[j] = (short)f2bf_u(Wih[g * 128 + col]);
      }
      aY[i][kt] = r;
    }
    #pragma unroll
    for (int c = 0; c < 2; c++){
      short8 r;
      #pragma unroll
      for (int j = 0; j < 8; j++)
        r[j] = (short)f2bf_u(Whh[g * 64 + sigma_p(c * 32 + quad * 8 + j)]);
      aH[i][c] = r;
    }
    const int gu = 4 * rt + quad;
    #pragma unroll
    for (int r = 0; r < 4; r++) biasv[i][r] = bih[r * 64 + gu] + bhh[r * 64 + gu];
  }

  for (int idx = tid; idx < 2 * 16 * LSTR; idx += 512)
    ((unsigned short*)sZ)[idx] = 0;
  __syncthreads();

  const size_t brow = (size_t)(bbase + (m16 & 7)) * TT;
  const int coff = quad * 8;
  float c0 = 0.f, c1 = 0.f;
  const int hpos = 4 * wv + quad;

  // 4-slot register prefetch of y0 fragments
  short8 F0[4], F1[4], F2[4], F3[4];
  #define LOADF(DST, S) do { \
      int sg = (S); if (sg > TT - 1) sg = TT - 1; \
      const int tg = dir ? (TT - 1 - sg) : sg; \
      const unsigned short* yb = y0 + (brow + tg) * 128; \
      DST[0] = *(const short8*)(yb +      coff); \
      DST[1] = *(const short8*)(yb + 32 + coff); \
      DST[2] = *(const short8*)(yb + 64 + coff); \
      DST[3] = *(const short8*)(yb + 96 + coff); \
    } while(0)
  LOADF(F0, 0); LOADF(F1, 1); LOADF(F2, 2); LOADF(F3, 3);

  f32x4 accY[2];
  #pragma unroll
  for (int i = 0; i < 2; i++){
    f32x4 a = biasv[i];
    a = MF(aY[i][0], F0[0], a); a = MF(aY[i][1], F0[1], a);
    a = MF(aY[i][2], F0[2], a); a = MF(aY[i][3], F0[3], a);
    accY[i] = a;
  }

#define L1STEP(S, FN, FL) do { \
    const int p = (S) & 1, p1 = p ^ 1; \
    short8 bh0 = *(const short8*)&sZ[p][m16][     quad * 8]; \
    short8 bh1 = *(const short8*)&sZ[p][m16][32 + quad * 8]; \
    f32x4 a0, a1; \
    a0 = MF(aH[0][0], bh0, accY[0]);  a1 = MF(aH[1][0], bh0, accY[1]); \
    a0 = MF(aH[0][1], bh1, a0);       a1 = MF(aH[1][1], bh1, a1); \
    float h0, h1; \
    { float ip = sigf(a0[0]), fp = sigf(a0[1]), gp = tanh_f(a0[2]), op = sigf(a0[3]); \
      c0 = fmaf(fp, c0, ip * gp); h0 = op * tanh_f(c0); } \
    { float ip = sigf(a1[0]), fp = sigf(a1[1]), gp = tanh_f(a1[2]), op = sigf(a1[3]); \
      c1 = fmaf(fp, c1, ip * gp); h1 = op * tanh_f(c1); } \
    if (m16 < 8){ \
      ((uint32_t*)&sZ[p1][m16][0])[hpos] = f2bf_u(h0) | (f2bf_u(h1) << 16); \
      if ((S) == TT - 1){ \
        const int u0 = 8 * wv + quad; \
        hT[(size_t)(bbase + m16) * 128 + dir * 64 + u0] = h0; \
        hT[(size_t)(bbase + m16) * 128 + dir * 64 + u0 + 4] = h1; \
      } \
    } \
    /* shadow: accY for S+1 from FN; refill FL for S+4 */ \
    _Pragma("unroll") \
    for (int i = 0; i < 2; i++){ \
      f32x4 a = biasv[i]; \
      a = MF(aY[i][0], FN[0], a); a = MF(aY[i][1], FN[1], a); \
      a = MF(aY[i][2], FN[2], a); a = MF(aY[i][3], FN[3], a); \
      accY[i] = a; \
    } \
    LOADF(FL, (S) + 4); \
    lds_barrier(); \
  } while(0)

  for (int s = 0; s < TT; s += 4){
    L1STEP(s + 0, F1, F0);
    L1STEP(s + 1, F2, F1);
    L1STEP(s + 2, F3, F2);
    L1STEP(s + 3, F0, F3);
  }
#undef L1STEP
#undef LOADF
}

// ==================== FC head ====================
__global__ __launch_bounds__(256, 1) void fc_kernel(
    const float* __restrict__ hT,
    const float* __restrict__ w1, const float* __restrict__ b1,
    const float* __restrict__ w2, const float* __restrict__ b2,
    float* __restrict__ out)
{
  __shared__ float sh[4][64];
  const int wave = threadIdx.x >> 6, lane = threadIdx.x & 63;
  const int b = blockIdx.x * 4 + wave;
  float acc = b1[lane];
  const float* hrow = hT + (size_t)b * 128;
  #pragma unroll
  for (int k = 0; k < 128; k += 4){
    float4 h4 = *(const float4*)(hrow + k);
    float4 w4 = *(const float4*)(w1 + lane * 128 + k);
    acc = fmaf(w4.x, h4.x, acc);
    acc = fmaf(w4.y, h4.y, acc);
    acc = fmaf(w4.z, h4.z, acc);
    acc = fmaf(w4.w, h4.w, acc);
  }
  sh[wave][lane] = fmaxf(acc, 0.f);
  __syncthreads();
  if (lane < 2){
    float a = b2[lane];
    #pragma unroll
    for (int k = 0; k < 64; k++) a = fmaf(w2[lane * 64 + k], sh[wave][k], a);
    out[(size_t)b * 2 + lane] = a;
  }
}

extern "C" void kernel_launch(void* const* d_in, const int* in_sizes, int n_in,
                              void* d_out, int out_size, void* d_ws, size_t ws_size,
                              hipStream_t stream){
  (void)in_sizes; (void)n_in; (void)out_size; (void)ws_size;
  const float* x     = (const float*)d_in[0];
  const float* Wih0f = (const float*)d_in[1];
  const float* Whh0f = (const float*)d_in[2];
  const float* bih0f = (const float*)d_in[3];
  const float* bhh0f = (const float*)d_in[4];
  const float* Wih0b = (const float*)d_in[5];
  const float* Whh0b = (const float*)d_in[6];
  const float* bih0b = (const float*)d_in[7];
  const float* bhh0b = (const float*)d_in[8];
  const float* Wih1f = (const float*)d_in[9];
  const float* Whh1f = (const float*)d_in[10];
  const float* bih1f = (const float*)d_in[11];
  const float* bhh1f = (const float*)d_in[12];
  const float* Wih1b = (const float*)d_in[13];
  const float* Whh1b = (const float*)d_in[14];
  const float* bih1b = (const float*)d_in[15];
  const float* bhh1b = (const float*)d_in[16];
  const float* fc1W  = (const float*)d_in[17];
  const float* fc1b  = (const float*)d_in[18];
  const float* fc2W  = (const float*)d_in[19];
  const float* fc2b  = (const float*)d_in[20];
  float* out = (float*)d_out;

  unsigned short* y0 = (unsigned short*)d_ws;                       // 134,217,728 B
  float* hT = (float*)((char*)d_ws + (size_t)1024 * TT * 128 * 2);

  dim3 grid(128, 2), block(512);
  lstm_l0<<<grid, block, 0, stream>>>(x, Wih0f, Whh0f, bih0f, bhh0f,
                                      Wih0b, Whh0b, bih0b, bhh0b, y0);
  lstm_l1<<<grid, block, 0, stream>>>(y0, Wih1f, Whh1f, bih1f, bhh1f,
                                      Wih1b, Whh1b, bih1b, bhh1b, hT);
  fc_kernel<<<dim3(256), dim3(256), 0, stream>>>(hT, fc1W, fc1b, fc2W, fc2b, out);
}